// Round 1
// baseline (439.603 us; speedup 1.0000x reference)
//
#include <hip/hip_runtime.h>
#include <hip/hip_bf16.h>

#define VOCAB 50000
#define SEQ   200

// One block per batch row:
//  phase 1: zero the 50000-float output row with coalesced float4 stores
//  phase 2: 200 atomicAdd(+1.0f) scatters into the (now L2-hot) row.
// __syncthreads() between phases drains vmcnt(0), so the zero stores are
// visible in L2 before the atomics RMW the same lines (same CU -> same XCD L2).
__global__ __launch_bounds__(256) void MultihotEmbedding_16458314678493_kernel(
    const int* __restrict__ x, float* __restrict__ out) {
  const int row = blockIdx.x;
  float* __restrict__ orow = out + (size_t)row * VOCAB;

  // 50000 floats = 12500 float4; row byte offset = row*200000, 16B-aligned.
  float4* __restrict__ o4 = (float4*)orow;
  const float4 z = make_float4(0.f, 0.f, 0.f, 0.f);
  #pragma unroll 4
  for (int i = threadIdx.x; i < VOCAB / 4; i += 256) {
    o4[i] = z;
  }
  __syncthreads();

  const int* __restrict__ xr = x + row * SEQ;
  for (int t = threadIdx.x; t < SEQ; t += 256) {
    atomicAdd(&orow[xr[t]], 1.0f);
  }
}

extern "C" void kernel_launch(void* const* d_in, const int* in_sizes, int n_in,
                              void* d_out, int out_size, void* d_ws, size_t ws_size,
                              hipStream_t stream) {
  const int* x = (const int*)d_in[0];
  float* out = (float*)d_out;
  const int batch = in_sizes[0] / SEQ;  // 409600 / 200 = 2048
  MultihotEmbedding_16458314678493_kernel<<<batch, 256, 0, stream>>>(x, out);
}

// Round 2
// 406.332 us; speedup vs baseline: 1.0819x; 1.0819x over previous
//
#include <hip/hip_runtime.h>
#include <hip/hip_bf16.h>

#define VOCAB 50000
#define SEQ   200
#define NDW   (VOCAB / 4)    // 12500 u32, each packing 4 u8 counts
#define NV4   (VOCAB / 16)   // 3125 uint4 for LDS zeroing

// One block per batch row. Whole 50000-bucket histogram lives in LDS as
// packed u8 counts (50 KB -> 3 blocks/CU). Max count per row = SEQ = 200
// < 256, so byte counters can't overflow and the packed u32 atomicAdd
// (1 << 8*(idx&3)) can never carry across a byte boundary.
// Output lines are written exactly once (no global atomics, no RMW refetch).
__global__ __launch_bounds__(256) void MultihotEmbedding_16458314678493_kernel(
    const int* __restrict__ x, float* __restrict__ out) {
  __shared__ unsigned cnt[NDW];

  // Phase 1: zero the LDS histogram (vectorized, 3125/256 ~= 12 iters).
  uint4* __restrict__ c4 = (uint4*)cnt;
  const uint4 z = make_uint4(0u, 0u, 0u, 0u);
  for (int i = threadIdx.x; i < NV4; i += 256) c4[i] = z;
  __syncthreads();

  // Phase 2: 200 LDS atomics (threads 0..199, one each).
  const int row = blockIdx.x;
  const int* __restrict__ xr = x + row * SEQ;
  for (int t = threadIdx.x; t < SEQ; t += 256) {
    const int idx = xr[t];
    atomicAdd(&cnt[idx >> 2], 1u << ((idx & 3) * 8));
  }
  __syncthreads();

  // Phase 3: stream out. 1 ds_read_b32 (4 counts) -> 1 global float4 store.
  // Lane i reads dword i: stride-1, conflict-free (2 lanes/bank is free).
  float4* __restrict__ o4 = (float4*)(out + (size_t)row * VOCAB);
  for (int i = threadIdx.x; i < NDW; i += 256) {
    const unsigned u = cnt[i];
    float4 v;
    v.x = (float)(u & 0xffu);
    v.y = (float)((u >> 8) & 0xffu);
    v.z = (float)((u >> 16) & 0xffu);
    v.w = (float)(u >> 24);
    o4[i] = v;
  }
}

extern "C" void kernel_launch(void* const* d_in, const int* in_sizes, int n_in,
                              void* d_out, int out_size, void* d_ws, size_t ws_size,
                              hipStream_t stream) {
  const int* x = (const int*)d_in[0];
  float* out = (float*)d_out;
  const int batch = in_sizes[0] / SEQ;  // 2048
  MultihotEmbedding_16458314678493_kernel<<<batch, 256, 0, stream>>>(x, out);
}